// Round 1
// baseline (1002.371 us; speedup 1.0000x reference)
//
#include <hip/hip_runtime.h>
#include <cstdint>

// InstantNGP hash-grid encoder, MI355X.
// D=3, L=16, F=2, N_MIN=16, PLS=2 -> scale_l = 16*2^l - 1, res_l = 16*2^l.
// Levels 0..2 dense (mod is a no-op: idx < (res+1)^3 == hmap), levels 3..15
// hashed with hmap = 2^19 (mask 0x7FFFF).
// Two kernels of 8 levels each: 16 acc VGPRs/thread, each point's store is a
// full 64B line (4x float4) -> no partial-line RMW at DRAM.

static constexpr uint32_t kOff[17] = {
    0u, 4913u, 40850u, 315475u, 839763u, 1364051u, 1888339u, 2412627u,
    2936915u, 3461203u, 3985491u, 4509779u, 5034067u, 5558355u, 6082643u,
    6606931u, 7131219u};

template <int LV>
__device__ __forceinline__ void level_accum(float x0, float x1, float x2,
                                            const float2* __restrict__ emb,
                                            float& a0, float& a1) {
  constexpr uint32_t res = 16u << LV;
  constexpr float scale = (float)res - 1.0f;  // 16*2^l - 1, exact in f32
  constexpr bool use_hash = (LV >= 3);
  constexpr uint32_t off = kOff[LV];

  // pos = x*scale + 0.5, deliberately NOT contracted to fma (match reference
  // separate-rounding semantics; floor-boundary safety).
  float p0 = __fadd_rn(__fmul_rn(x0, scale), 0.5f);
  float p1 = __fadd_rn(__fmul_rn(x1, scale), 0.5f);
  float p2 = __fadd_rn(__fmul_rn(x2, scale), 0.5f);
  float pf0 = floorf(p0), pf1 = floorf(p1), pf2 = floorf(p2);
  float f0 = __fsub_rn(p0, pf0);
  float f1 = __fsub_rn(p1, pf1);
  float f2 = __fsub_rn(p2, pf2);
  uint32_t i0 = (uint32_t)pf0, i1 = (uint32_t)pf1, i2 = (uint32_t)pf2;

  float w0[2] = {__fsub_rn(1.0f, f0), f0};
  float w1[2] = {__fsub_rn(1.0f, f1), f1};
  float w2[2] = {__fsub_rn(1.0f, f2), f2};

  uint32_t h0[2], h1[2], h2[2];
  if (use_hash) {
    h0[0] = i0;                h0[1] = i0 + 1u;
    h1[0] = i1 * 2654435761u;  h1[1] = h1[0] + 2654435761u;
    h2[0] = i2 * 805459861u;   h2[1] = h2[0] + 805459861u;
  } else {
    constexpr uint32_t s1 = res + 1u;
    constexpr uint32_t s2 = s1 * s1;
    h0[0] = i0;        h0[1] = i0 + 1u;
    h1[0] = i1 * s1;   h1[1] = h1[0] + s1;
    h2[0] = i2 * s2;   h2[1] = h2[0] + s2;
  }

  float acc0 = a0, acc1 = a1;
#pragma unroll
  for (int c = 0; c < 8; ++c) {
    const uint32_t b0 = c & 1, b1 = (c >> 1) & 1, b2 = (c >> 2) & 1;
    uint32_t idx;
    if (use_hash) {
      idx = (h0[b0] ^ h1[b1] ^ h2[b2]) & 0x7FFFFu;
    } else {
      idx = h0[b0] + h1[b1] + h2[b2];  // < hmap by construction
    }
    const float w = __fmul_rn(__fmul_rn(w0[b0], w1[b1]), w2[b2]);
    const float2 e = emb[off + idx];
    acc0 = __fadd_rn(acc0, __fmul_rn(w, e.x));
    acc1 = __fadd_rn(acc1, __fmul_rn(w, e.y));
  }
  a0 = acc0;
  a1 = acc1;
}

template <int LBASE>
__global__ __launch_bounds__(256) void grid_enc_kernel(
    const float* __restrict__ in, const float* __restrict__ embf,
    float* __restrict__ out, int B) {
  const int p = blockIdx.x * 256 + threadIdx.x;
  if (p >= B) return;
  const float2* __restrict__ emb = (const float2*)embf;

  const float xi0 = in[(size_t)p * 3 + 0];
  const float xi1 = in[(size_t)p * 3 + 1];
  const float xi2 = in[(size_t)p * 3 + 2];
  // x = (in + 1) * 0.5 (division by 2 == *0.5 exactly; no fma shape here)
  const float x0 = __fmul_rn(__fadd_rn(xi0, 1.0f), 0.5f);
  const float x1 = __fmul_rn(__fadd_rn(xi1, 1.0f), 0.5f);
  const float x2 = __fmul_rn(__fadd_rn(xi2, 1.0f), 0.5f);

  float a[16];
#pragma unroll
  for (int i = 0; i < 16; ++i) a[i] = 0.0f;

  level_accum<LBASE + 0>(x0, x1, x2, emb, a[0], a[1]);
  level_accum<LBASE + 1>(x0, x1, x2, emb, a[2], a[3]);
  level_accum<LBASE + 2>(x0, x1, x2, emb, a[4], a[5]);
  level_accum<LBASE + 3>(x0, x1, x2, emb, a[6], a[7]);
  level_accum<LBASE + 4>(x0, x1, x2, emb, a[8], a[9]);
  level_accum<LBASE + 5>(x0, x1, x2, emb, a[10], a[11]);
  level_accum<LBASE + 6>(x0, x1, x2, emb, a[12], a[13]);
  level_accum<LBASE + 7>(x0, x1, x2, emb, a[14], a[15]);

  // 64B-aligned full-line store: out row = 32 floats, this kernel owns
  // floats [LBASE*2, LBASE*2+16) = one 64B line.
  float4* __restrict__ o = (float4*)(out + (size_t)p * 32 + LBASE * 2);
  o[0] = make_float4(a[0], a[1], a[2], a[3]);
  o[1] = make_float4(a[4], a[5], a[6], a[7]);
  o[2] = make_float4(a[8], a[9], a[10], a[11]);
  o[3] = make_float4(a[12], a[13], a[14], a[15]);
}

extern "C" void kernel_launch(void* const* d_in, const int* in_sizes, int n_in,
                              void* d_out, int out_size, void* d_ws,
                              size_t ws_size, hipStream_t stream) {
  const float* in = (const float*)d_in[0];
  const float* emb = (const float*)d_in[1];
  float* out = (float*)d_out;
  const int B = in_sizes[0] / 3;
  const int blocks = (B + 255) / 256;
  grid_enc_kernel<0><<<blocks, 256, 0, stream>>>(in, emb, out, B);
  grid_enc_kernel<8><<<blocks, 256, 0, stream>>>(in, emb, out, B);
}

// Round 2
// 763.486 us; speedup vs baseline: 1.3129x; 1.3129x over previous
//
#include <hip/hip_runtime.h>
#include <cstdint>

// InstantNGP hash-grid encoder, MI355X, v2: level-split for L2 residency.
// D=3, L=16, F=2, N_MIN=16, PLS=2 -> scale_l = 16*2^l - 1, res_l = 16*2^l.
// Levels 0..2 dense (2.5 MB total, mod is a no-op), levels 3..15 hashed with
// hmap = 2^19 (mask 0x7FFFF) -> each table is exactly 4 MB = one XCD L2.
// v1 lesson (rocprof): 8 levels/kernel = 32 MB gather working set >> 4 MB L2
// -> 1.73 GB FETCH_SIZE/dispatch, 47% HBM, 1002 us. Fix: one kernel per
// hashed level so the 4 MB table is L2-resident; level outputs go to ws in
// [level][point] float2 layout (full-line coalesced writes), final transpose
// kernel assembles [point][32]. Fallback to v1 path if ws too small.

static constexpr uint32_t kOff[17] = {
    0u, 4913u, 40850u, 315475u, 839763u, 1364051u, 1888339u, 2412627u,
    2936915u, 3461203u, 3985491u, 4509779u, 5034067u, 5558355u, 6082643u,
    6606931u, 7131219u};

template <int LV>
__device__ __forceinline__ void level_accum(float x0, float x1, float x2,
                                            const float2* __restrict__ emb,
                                            float& a0, float& a1) {
  constexpr uint32_t res = 16u << LV;
  constexpr float scale = (float)res - 1.0f;  // 16*2^l - 1, exact in f32
  constexpr bool use_hash = (LV >= 3);
  constexpr uint32_t off = kOff[LV];

  // pos = x*scale + 0.5, deliberately NOT contracted to fma (match reference
  // separate-rounding semantics; floor-boundary safety).
  float p0 = __fadd_rn(__fmul_rn(x0, scale), 0.5f);
  float p1 = __fadd_rn(__fmul_rn(x1, scale), 0.5f);
  float p2 = __fadd_rn(__fmul_rn(x2, scale), 0.5f);
  float pf0 = floorf(p0), pf1 = floorf(p1), pf2 = floorf(p2);
  float f0 = __fsub_rn(p0, pf0);
  float f1 = __fsub_rn(p1, pf1);
  float f2 = __fsub_rn(p2, pf2);
  uint32_t i0 = (uint32_t)pf0, i1 = (uint32_t)pf1, i2 = (uint32_t)pf2;

  float w0[2] = {__fsub_rn(1.0f, f0), f0};
  float w1[2] = {__fsub_rn(1.0f, f1), f1};
  float w2[2] = {__fsub_rn(1.0f, f2), f2};

  uint32_t h0[2], h1[2], h2[2];
  if (use_hash) {
    h0[0] = i0;                h0[1] = i0 + 1u;
    h1[0] = i1 * 2654435761u;  h1[1] = h1[0] + 2654435761u;
    h2[0] = i2 * 805459861u;   h2[1] = h2[0] + 805459861u;
  } else {
    constexpr uint32_t s1 = res + 1u;
    constexpr uint32_t s2 = s1 * s1;
    h0[0] = i0;        h0[1] = i0 + 1u;
    h1[0] = i1 * s1;   h1[1] = h1[0] + s1;
    h2[0] = i2 * s2;   h2[1] = h2[0] + s2;
  }

  float acc0 = a0, acc1 = a1;
#pragma unroll
  for (int c = 0; c < 8; ++c) {
    const uint32_t b0 = c & 1, b1 = (c >> 1) & 1, b2 = (c >> 2) & 1;
    uint32_t idx;
    if (use_hash) {
      idx = (h0[b0] ^ h1[b1] ^ h2[b2]) & 0x7FFFFu;
    } else {
      idx = h0[b0] + h1[b1] + h2[b2];  // < hmap by construction
    }
    const float w = __fmul_rn(__fmul_rn(w0[b0], w1[b1]), w2[b2]);
    const float2 e = emb[off + idx];
    acc0 = __fadd_rn(acc0, __fmul_rn(w, e.x));
    acc1 = __fadd_rn(acc1, __fmul_rn(w, e.y));
  }
  a0 = acc0;
  a1 = acc1;
}

__device__ __forceinline__ void load_x(const float* __restrict__ in, int p,
                                       float& x0, float& x1, float& x2) {
  const float xi0 = in[(size_t)p * 3 + 0];
  const float xi1 = in[(size_t)p * 3 + 1];
  const float xi2 = in[(size_t)p * 3 + 2];
  x0 = __fmul_rn(__fadd_rn(xi0, 1.0f), 0.5f);
  x1 = __fmul_rn(__fadd_rn(xi1, 1.0f), 0.5f);
  x2 = __fmul_rn(__fadd_rn(xi2, 1.0f), 0.5f);
}

// ---------------- v2 path: one kernel per hashed level ----------------

template <int LV>
__global__ __launch_bounds__(256) void level_kernel(
    const float* __restrict__ in, const float* __restrict__ embf,
    float2* __restrict__ ws, int B) {
  const int p = blockIdx.x * 256 + threadIdx.x;
  if (p >= B) return;
  float x0, x1, x2;
  load_x(in, p, x0, x1, x2);
  float a0 = 0.0f, a1 = 0.0f;
  level_accum<LV>(x0, x1, x2, (const float2*)embf, a0, a1);
  ws[(size_t)LV * B + p] = make_float2(a0, a1);
}

// Dense levels 0..2 in one kernel (2.5 MB tables, spatially local).
__global__ __launch_bounds__(256) void dense_kernel(
    const float* __restrict__ in, const float* __restrict__ embf,
    float2* __restrict__ ws, int B) {
  const int p = blockIdx.x * 256 + threadIdx.x;
  if (p >= B) return;
  float x0, x1, x2;
  load_x(in, p, x0, x1, x2);
  const float2* emb = (const float2*)embf;
  float a0, a1;
  a0 = a1 = 0.0f; level_accum<0>(x0, x1, x2, emb, a0, a1);
  ws[(size_t)0 * B + p] = make_float2(a0, a1);
  a0 = a1 = 0.0f; level_accum<1>(x0, x1, x2, emb, a0, a1);
  ws[(size_t)1 * B + p] = make_float2(a0, a1);
  a0 = a1 = 0.0f; level_accum<2>(x0, x1, x2, emb, a0, a1);
  ws[(size_t)2 * B + p] = make_float2(a0, a1);
}

// Final pass: [16][B] float2 -> [B][32] float, both sides coalesced.
__global__ __launch_bounds__(256) void transpose_kernel(
    const float2* __restrict__ ws, float4* __restrict__ out, int B) {
  const int p = blockIdx.x * 256 + threadIdx.x;
  if (p >= B) return;
  float4 o[8];
#pragma unroll
  for (int l = 0; l < 16; l += 2) {
    const float2 e0 = ws[(size_t)l * B + p];
    const float2 e1 = ws[(size_t)(l + 1) * B + p];
    o[l >> 1] = make_float4(e0.x, e0.y, e1.x, e1.y);
  }
  float4* __restrict__ dst = out + (size_t)p * 8;
#pragma unroll
  for (int i = 0; i < 8; ++i) dst[i] = o[i];
}

// ---------------- v1 fallback (ws too small): 8 levels/kernel ----------------

template <int LBASE>
__global__ __launch_bounds__(256) void grid_enc_kernel(
    const float* __restrict__ in, const float* __restrict__ embf,
    float* __restrict__ out, int B) {
  const int p = blockIdx.x * 256 + threadIdx.x;
  if (p >= B) return;
  const float2* __restrict__ emb = (const float2*)embf;
  float x0, x1, x2;
  load_x(in, p, x0, x1, x2);

  float a[16];
#pragma unroll
  for (int i = 0; i < 16; ++i) a[i] = 0.0f;

  level_accum<LBASE + 0>(x0, x1, x2, emb, a[0], a[1]);
  level_accum<LBASE + 1>(x0, x1, x2, emb, a[2], a[3]);
  level_accum<LBASE + 2>(x0, x1, x2, emb, a[4], a[5]);
  level_accum<LBASE + 3>(x0, x1, x2, emb, a[6], a[7]);
  level_accum<LBASE + 4>(x0, x1, x2, emb, a[8], a[9]);
  level_accum<LBASE + 5>(x0, x1, x2, emb, a[10], a[11]);
  level_accum<LBASE + 6>(x0, x1, x2, emb, a[12], a[13]);
  level_accum<LBASE + 7>(x0, x1, x2, emb, a[14], a[15]);

  float4* __restrict__ o = (float4*)(out + (size_t)p * 32 + LBASE * 2);
  o[0] = make_float4(a[0], a[1], a[2], a[3]);
  o[1] = make_float4(a[4], a[5], a[6], a[7]);
  o[2] = make_float4(a[8], a[9], a[10], a[11]);
  o[3] = make_float4(a[12], a[13], a[14], a[15]);
}

extern "C" void kernel_launch(void* const* d_in, const int* in_sizes, int n_in,
                              void* d_out, int out_size, void* d_ws,
                              size_t ws_size, hipStream_t stream) {
  const float* in = (const float*)d_in[0];
  const float* emb = (const float*)d_in[1];
  float* out = (float*)d_out;
  const int B = in_sizes[0] / 3;
  const int blocks = (B + 255) / 256;
  const size_t ws_needed = (size_t)16 * (size_t)B * sizeof(float2);

  if (ws_size >= ws_needed) {
    float2* ws = (float2*)d_ws;
    dense_kernel<<<blocks, 256, 0, stream>>>(in, emb, ws, B);
    level_kernel<3><<<blocks, 256, 0, stream>>>(in, emb, ws, B);
    level_kernel<4><<<blocks, 256, 0, stream>>>(in, emb, ws, B);
    level_kernel<5><<<blocks, 256, 0, stream>>>(in, emb, ws, B);
    level_kernel<6><<<blocks, 256, 0, stream>>>(in, emb, ws, B);
    level_kernel<7><<<blocks, 256, 0, stream>>>(in, emb, ws, B);
    level_kernel<8><<<blocks, 256, 0, stream>>>(in, emb, ws, B);
    level_kernel<9><<<blocks, 256, 0, stream>>>(in, emb, ws, B);
    level_kernel<10><<<blocks, 256, 0, stream>>>(in, emb, ws, B);
    level_kernel<11><<<blocks, 256, 0, stream>>>(in, emb, ws, B);
    level_kernel<12><<<blocks, 256, 0, stream>>>(in, emb, ws, B);
    level_kernel<13><<<blocks, 256, 0, stream>>>(in, emb, ws, B);
    level_kernel<14><<<blocks, 256, 0, stream>>>(in, emb, ws, B);
    level_kernel<15><<<blocks, 256, 0, stream>>>(in, emb, ws, B);
    transpose_kernel<<<blocks, 256, 0, stream>>>(ws, (float4*)out, B);
  } else {
    grid_enc_kernel<0><<<blocks, 256, 0, stream>>>(in, emb, out, B);
    grid_enc_kernel<8><<<blocks, 256, 0, stream>>>(in, emb, out, B);
  }
}

// Round 3
// 678.246 us; speedup vs baseline: 1.4779x; 1.1257x over previous
//
#include <hip/hip_runtime.h>
#include <cstdint>

// InstantNGP hash-grid encoder, MI355X, v3.
// D=3, L=16, F=2, N_MIN=16, PLS=2 -> scale_l = 16*2^l - 1, res_l = 16*2^l.
// Levels 0..2 dense (mod provably no-op), levels 3..15 hashed, hmap=2^19.
// v2 lessons (rocprof): transpose kernel wrote 452 MB for a 128 MB output
// (partial-line 128B-stride stores don't merge under read pressure) and took
// 150 us; level kernels ~41 us each (latency-bound, VALUBusy ~0.3%).
// v3: (1) final kernel does LDS block-transpose -> every global store is a
// wave-contiguous 1KB full line; (2) dense levels fused into final kernel;
// (3) level kernels process 2 points/thread and merge corner pairs:
// hashed idx_hi == idx_lo^1 when i0 even -> one 16B (8B-aligned) load covers
// both corners; dense corners always adjacent -> always one 16B load.

static constexpr uint32_t kOff[17] = {
    0u, 4913u, 40850u, 315475u, 839763u, 1364051u, 1888339u, 2412627u,
    2936915u, 3461203u, 3985491u, 4509779u, 5034067u, 5558355u, 6082643u,
    6606931u, 7131219u};

static constexpr uint32_t P1 = 2654435761u;
static constexpr uint32_t P2 = 805459861u;

// 16B vector with 8B alignment: gfx950 global loads support dword alignment
// (unaligned-access mode), so clang emits a single global_load_dwordx4.
typedef float f4a8 __attribute__((ext_vector_type(4), aligned(8)));

__device__ __forceinline__ float to_unit(float v) {
  // x = (in + 1) / 2 ; *0.5 is exact, matches reference
  return __fmul_rn(__fadd_rn(v, 1.0f), 0.5f);
}

// Position decomposition for level LV. pos = x*scale + 0.5 with separate
// mul/add rounding (match reference, no fma contraction).
template <int LV>
__device__ __forceinline__ void pos_decomp(float x0, float x1, float x2,
                                           uint32_t& i0, uint32_t& i1,
                                           uint32_t& i2, float& f0, float& f1,
                                           float& f2) {
  constexpr float scale = (float)(16u << LV) - 1.0f;  // exact in f32
  float p0 = __fadd_rn(__fmul_rn(x0, scale), 0.5f);
  float p1 = __fadd_rn(__fmul_rn(x1, scale), 0.5f);
  float p2 = __fadd_rn(__fmul_rn(x2, scale), 0.5f);
  float g0 = floorf(p0), g1 = floorf(p1), g2 = floorf(p2);
  f0 = __fsub_rn(p0, g0);
  f1 = __fsub_rn(p1, g1);
  f2 = __fsub_rn(p2, g2);
  i0 = (uint32_t)g0;
  i1 = (uint32_t)g1;
  i2 = (uint32_t)g2;
}

// Hashed level (LV >= 3): 4 pair-loads + predicated fixup for odd i0.
// Reference corner order c=0..7 == b2 outer, b1 mid, b0 inner; weight
// association ((w0*w1)*w2) and per-corner mul-then-add preserved.
template <int LV>
__device__ __forceinline__ void hashed_accum(float x0, float x1, float x2,
                                             const float* __restrict__ embf,
                                             float& A0, float& A1) {
  static_assert(LV >= 3, "");
  constexpr uint32_t off = kOff[LV];
  constexpr uint32_t mask = 0x7FFFFu;  // hmap = 2^19
  uint32_t i0, i1, i2;
  float f0, f1, f2;
  pos_decomp<LV>(x0, x1, x2, i0, i1, i2, f0, f1, f2);

  const float w0l = __fsub_rn(1.0f, f0), w0h = f0;
  const float w1v[2] = {__fsub_rn(1.0f, f1), f1};
  const float w2v[2] = {__fsub_rn(1.0f, f2), f2};
  uint32_t h1v[2], h2v[2];
  h1v[0] = i1 * P1;
  h1v[1] = h1v[0] + P1;
  h2v[0] = i2 * P2;
  h2v[1] = h2v[0] + P2;

  const float2* t2 = (const float2*)embf + off;
  const bool odd = (i0 & 1u) != 0u;

  float acc0 = A0, acc1 = A1;
#pragma unroll
  for (int b2 = 0; b2 < 2; ++b2) {
#pragma unroll
    for (int b1 = 0; b1 < 2; ++b1) {
      const uint32_t ex = h1v[b1] ^ h2v[b2];
      const uint32_t ilo = (i0 ^ ex) & mask;
      // 16B load covering entries {ilo & ~1, ilo | 1}
      const f4a8 v = *(const f4a8*)(t2 + (ilo & ~1u));
      const bool hs = (ilo & 1u) != 0u;
      float eL0 = hs ? v.z : v.x;
      float eL1 = hs ? v.w : v.y;
      float eH0 = hs ? v.x : v.z;  // valid when i0 even (ihi == ilo^1)
      float eH1 = hs ? v.y : v.w;
      if (odd) {
        const uint32_t ihi = ((i0 + 1u) ^ ex) & mask;
        const float2 e = t2[ihi];
        eH0 = e.x;
        eH1 = e.y;
      }
      const float wl = __fmul_rn(__fmul_rn(w0l, w1v[b1]), w2v[b2]);
      const float wh = __fmul_rn(__fmul_rn(w0h, w1v[b1]), w2v[b2]);
      acc0 = __fadd_rn(acc0, __fmul_rn(wl, eL0));
      acc1 = __fadd_rn(acc1, __fmul_rn(wl, eL1));
      acc0 = __fadd_rn(acc0, __fmul_rn(wh, eH0));
      acc1 = __fadd_rn(acc1, __fmul_rn(wh, eH1));
    }
  }
  A0 = acc0;
  A1 = acc1;
}

// Dense level (LV < 3): corner pair always adjacent -> one 16B load covers
// both {idx, idx+1}; idx+1 is the b0=1 corner, always in-bounds.
template <int LV>
__device__ __forceinline__ void dense_accum(float x0, float x1, float x2,
                                            const float* __restrict__ embf,
                                            float& A0, float& A1) {
  static_assert(LV < 3, "");
  constexpr uint32_t res = 16u << LV;
  constexpr uint32_t off = kOff[LV];
  constexpr uint32_t s1 = res + 1u, s2 = s1 * s1;
  uint32_t i0, i1, i2;
  float f0, f1, f2;
  pos_decomp<LV>(x0, x1, x2, i0, i1, i2, f0, f1, f2);

  const float w0l = __fsub_rn(1.0f, f0), w0h = f0;
  const float w1v[2] = {__fsub_rn(1.0f, f1), f1};
  const float w2v[2] = {__fsub_rn(1.0f, f2), f2};
  const uint32_t base = i0 + i1 * s1 + i2 * s2;
  const float2* t2 = (const float2*)embf + off;

  float acc0 = A0, acc1 = A1;
#pragma unroll
  for (int b2 = 0; b2 < 2; ++b2) {
#pragma unroll
    for (int b1 = 0; b1 < 2; ++b1) {
      const uint32_t idx = base + (b1 ? s1 : 0u) + (b2 ? s2 : 0u);
      const f4a8 v = *(const f4a8*)(t2 + idx);  // {e[idx], e[idx+1]}
      const float wl = __fmul_rn(__fmul_rn(w0l, w1v[b1]), w2v[b2]);
      const float wh = __fmul_rn(__fmul_rn(w0h, w1v[b1]), w2v[b2]);
      acc0 = __fadd_rn(acc0, __fmul_rn(wl, v.x));
      acc1 = __fadd_rn(acc1, __fmul_rn(wl, v.y));
      acc0 = __fadd_rn(acc0, __fmul_rn(wh, v.z));
      acc1 = __fadd_rn(acc1, __fmul_rn(wh, v.w));
    }
  }
  A0 = acc0;
  A1 = acc1;
}

template <int LV>
__device__ __forceinline__ void any_accum(float x0, float x1, float x2,
                                          const float* __restrict__ embf,
                                          float& A0, float& A1) {
  if constexpr (LV < 3)
    dense_accum<LV>(x0, x1, x2, embf, A0, A1);
  else
    hashed_accum<LV>(x0, x1, x2, embf, A0, A1);
}

// ---------------- per-level gather kernels (2 points/thread) ----------------

template <int LV>
__global__ __launch_bounds__(256) void level_kernel(
    const float* __restrict__ in, const float* __restrict__ embf,
    float2* __restrict__ ws, int B) {
  const int q = blockIdx.x * 256 + threadIdx.x;
  const int p0 = q << 1;
  if (p0 >= B) return;
  const int p1 = p0 + 1;
  // floats [3*p0 .. 3*p0+5] = float2 indices [3q, 3q+1, 3q+2]
  const float2* in2 = (const float2*)in;
  const size_t b3 = (size_t)q * 3;
  const float2 u0 = in2[b3], u1 = in2[b3 + 1], u2 = in2[b3 + 2];

  float a0 = 0.0f, a1 = 0.0f;
  hashed_accum<LV>(to_unit(u0.x), to_unit(u0.y), to_unit(u1.x), embf, a0, a1);

  float2* __restrict__ wsl = ws + (size_t)(LV - 3) * B;
  if (((B & 1) == 0) && p1 < B) {
    float b0 = 0.0f, b1f = 0.0f;
    hashed_accum<LV>(to_unit(u1.y), to_unit(u2.x), to_unit(u2.y), embf, b0,
                     b1f);
    // (LV-3)*B + p0 is even (B even, p0 even) -> 16B-aligned float4 store
    *reinterpret_cast<float4*>(wsl + p0) = make_float4(a0, a1, b0, b1f);
  } else {
    wsl[p0] = make_float2(a0, a1);
    if (p1 < B) {
      float b0 = 0.0f, b1f = 0.0f;
      hashed_accum<LV>(to_unit(u1.y), to_unit(u2.x), to_unit(u2.y), embf, b0,
                       b1f);
      wsl[p1] = make_float2(b0, b1f);
    }
  }
}

// ------------- final kernel: dense levels + gather ws + transpose -------------

__global__ __launch_bounds__(256) void final_kernel(
    const float* __restrict__ in, const float* __restrict__ embf,
    const float2* __restrict__ ws, float4* __restrict__ out4, int B) {
  __shared__ float4 lds[8 * 257];  // [w][point], stride 257 breaks conflicts
  const int tid = threadIdx.x;
  const int p = blockIdx.x * 256 + tid;

  float a[32];
#pragma unroll
  for (int i = 0; i < 32; ++i) a[i] = 0.0f;

  if (p < B) {
    const float x0 = to_unit(in[(size_t)p * 3 + 0]);
    const float x1 = to_unit(in[(size_t)p * 3 + 1]);
    const float x2 = to_unit(in[(size_t)p * 3 + 2]);
    dense_accum<0>(x0, x1, x2, embf, a[0], a[1]);
    dense_accum<1>(x0, x1, x2, embf, a[2], a[3]);
    dense_accum<2>(x0, x1, x2, embf, a[4], a[5]);
#pragma unroll
    for (int l = 3; l < 16; ++l) {
      const float2 e = ws[(size_t)(l - 3) * B + p];
      a[2 * l] = e.x;
      a[2 * l + 1] = e.y;
    }
  }

#pragma unroll
  for (int w = 0; w < 8; ++w)
    lds[w * 257 + tid] = make_float4(a[4 * w], a[4 * w + 1], a[4 * w + 2],
                                     a[4 * w + 3]);
  __syncthreads();

  const size_t gbase = (size_t)blockIdx.x * 2048;
  const size_t lim = (size_t)B * 8;
#pragma unroll
  for (int j = 0; j < 8; ++j) {
    const int gl = j * 256 + tid;
    const size_t g = gbase + gl;
    if (g < lim) out4[g] = lds[(gl & 7) * 257 + (gl >> 3)];
  }
}

// ---------------- fallback (ws too small): 8 levels/kernel ----------------

template <int LBASE>
__global__ __launch_bounds__(256) void grid_enc_kernel(
    const float* __restrict__ in, const float* __restrict__ embf,
    float* __restrict__ out, int B) {
  const int p = blockIdx.x * 256 + threadIdx.x;
  if (p >= B) return;
  const float x0 = to_unit(in[(size_t)p * 3 + 0]);
  const float x1 = to_unit(in[(size_t)p * 3 + 1]);
  const float x2 = to_unit(in[(size_t)p * 3 + 2]);

  float a[16];
#pragma unroll
  for (int i = 0; i < 16; ++i) a[i] = 0.0f;

  any_accum<LBASE + 0>(x0, x1, x2, embf, a[0], a[1]);
  any_accum<LBASE + 1>(x0, x1, x2, embf, a[2], a[3]);
  any_accum<LBASE + 2>(x0, x1, x2, embf, a[4], a[5]);
  any_accum<LBASE + 3>(x0, x1, x2, embf, a[6], a[7]);
  any_accum<LBASE + 4>(x0, x1, x2, embf, a[8], a[9]);
  any_accum<LBASE + 5>(x0, x1, x2, embf, a[10], a[11]);
  any_accum<LBASE + 6>(x0, x1, x2, embf, a[12], a[13]);
  any_accum<LBASE + 7>(x0, x1, x2, embf, a[14], a[15]);

  float4* __restrict__ o = (float4*)(out + (size_t)p * 32 + LBASE * 2);
  o[0] = make_float4(a[0], a[1], a[2], a[3]);
  o[1] = make_float4(a[4], a[5], a[6], a[7]);
  o[2] = make_float4(a[8], a[9], a[10], a[11]);
  o[3] = make_float4(a[12], a[13], a[14], a[15]);
}

extern "C" void kernel_launch(void* const* d_in, const int* in_sizes, int n_in,
                              void* d_out, int out_size, void* d_ws,
                              size_t ws_size, hipStream_t stream) {
  const float* in = (const float*)d_in[0];
  const float* emb = (const float*)d_in[1];
  float* out = (float*)d_out;
  const int B = in_sizes[0] / 3;
  const int blocksP = (B + 255) / 256;            // one point/thread
  const int blocksQ = ((B + 1) / 2 + 255) / 256;  // two points/thread
  const size_t ws_needed = (size_t)13 * (size_t)B * sizeof(float2);

  if (ws_size >= ws_needed) {
    float2* ws = (float2*)d_ws;
    level_kernel<3><<<blocksQ, 256, 0, stream>>>(in, emb, ws, B);
    level_kernel<4><<<blocksQ, 256, 0, stream>>>(in, emb, ws, B);
    level_kernel<5><<<blocksQ, 256, 0, stream>>>(in, emb, ws, B);
    level_kernel<6><<<blocksQ, 256, 0, stream>>>(in, emb, ws, B);
    level_kernel<7><<<blocksQ, 256, 0, stream>>>(in, emb, ws, B);
    level_kernel<8><<<blocksQ, 256, 0, stream>>>(in, emb, ws, B);
    level_kernel<9><<<blocksQ, 256, 0, stream>>>(in, emb, ws, B);
    level_kernel<10><<<blocksQ, 256, 0, stream>>>(in, emb, ws, B);
    level_kernel<11><<<blocksQ, 256, 0, stream>>>(in, emb, ws, B);
    level_kernel<12><<<blocksQ, 256, 0, stream>>>(in, emb, ws, B);
    level_kernel<13><<<blocksQ, 256, 0, stream>>>(in, emb, ws, B);
    level_kernel<14><<<blocksQ, 256, 0, stream>>>(in, emb, ws, B);
    level_kernel<15><<<blocksQ, 256, 0, stream>>>(in, emb, ws, B);
    final_kernel<<<blocksP, 256, 0, stream>>>(in, emb, ws, (float4*)out, B);
  } else {
    grid_enc_kernel<0><<<blocksP, 256, 0, stream>>>(in, emb, out, B);
    grid_enc_kernel<8><<<blocksP, 256, 0, stream>>>(in, emb, out, B);
  }
}